// Round 12
// baseline (235.001 us; speedup 1.0000x reference)
//
#include <hip/hip_runtime.h>
#include <math.h>

namespace {
constexpr int E = 128, D = 256;
constexpr int NPOI = 10000, NH = 8, FFD = 256;
constexpr int HD = D / NH;            // 32
constexpr int NTOK = 4096;            // B*L
constexpr int TB = 4;                 // tokens/block, mha kernel, grid 1024
constexpr int TG = 16;                // tokens/group, embed kernel (dense M=16)
constexpr float LN_EPS = 1e-5f;

// packed bf16 weight layout offsets (ushort elements)
constexpr int PK_QKV = 0;             // 48 nt x 8 kt x 512
constexpr int PK_OUT = 196608;        // 16 x 8 x 512
constexpr int PK_FF1 = 262144;
constexpr int PK_FF2 = 327680;
constexpr int PK_E0  = 393216;        // [sp_w2;tok_w]  K=256: 16 nt x 8 kt
constexpr int PK_E1  = 458752;        // [te_w;tok_w]   K=640: 16 nt x 20 kt
constexpr int PK_E2  = 622592;        // [poi_w;tok_w]  K=256: 16 nt x 8 kt
constexpr int PK_TOTAL = 688128;
constexpr int NTILES = PK_TOTAL / 512;   // 1344 tiles, 1 per wave, 336 blocks
}

using frag8 = __attribute__((ext_vector_type(8))) short;   // 8 bf16 (4 VGPRs)
using f32x4 = __attribute__((ext_vector_type(4))) float;   // 4 fp32 acc

__device__ __forceinline__ float bf2f(short s) {
    union { unsigned u; float f; } x; x.u = ((unsigned)(unsigned short)s) << 16; return x.f;
}
__device__ __forceinline__ unsigned short f2bf(float f) {
    union { float f; unsigned u; } x; x.f = f;
    unsigned r = x.u + 0x7fffu + ((x.u >> 16) & 1u);
    return (unsigned short)(r >> 16);
}

// 64-lane wave sum
__device__ __forceinline__ float wsum64(float v) {
#pragma unroll
    for (int m = 1; m < 64; m <<= 1) v += __shfl_xor(v, m);
    return v;
}

// LayerNorm of a 128-vector by one wave; bf16 store to dst1 (and dst2 if non-null)
__device__ __forceinline__ void ln128_bf(const float* __restrict__ src,
                                         const float* __restrict__ g,
                                         const float* __restrict__ b,
                                         short* __restrict__ dst1,
                                         short* __restrict__ dst2, int lane) {
    float v0 = src[lane], v1 = src[64 + lane];
    float mean = wsum64(v0 + v1) * (1.0f / 128.0f);
    float d0 = v0 - mean, d1 = v1 - mean;
    float var = wsum64(d0 * d0 + d1 * d1) * (1.0f / 128.0f);
    float inv = sqrtf(var + LN_EPS);
    float y0 = d0 / inv * g[lane] + b[lane];
    float y1 = d1 / inv * g[64 + lane] + b[64 + lane];
    unsigned short s0 = f2bf(y0), s1 = f2bf(y1);
    dst1[lane] = (short)s0; dst1[64 + lane] = (short)s1;
    if (dst2) { dst2[lane] = (short)s0; dst2[64 + lane] = (short)s1; }
}

// ---------------- Weight prepack: coalesced reads, LDS transpose ----------------
__global__ __launch_bounds__(256)
void pack_weights(const float* __restrict__ wqkv, const float* __restrict__ wout,
                  const float* __restrict__ fw1,  const float* __restrict__ fw2,
                  const float* __restrict__ sp_w2, const float* __restrict__ te_w,
                  const float* __restrict__ poi_w, const float* __restrict__ tok_w,
                  unsigned short* __restrict__ pk)
{
    __shared__ float buf[4][32 * 17];        // per-wave 544 floats
    const int wv = threadIdx.x >> 6, lane = threadIdx.x & 63;
    const int tile = blockIdx.x * 4 + wv;
    if (tile >= NTILES) return;              // exact fit: 336*4 = 1344

    int t = tile, sel, base;
    if (t < 384)              { sel = 0; base = PK_QKV; }
    else if ((t -= 384) < 128){ sel = 1; base = PK_OUT; }
    else if ((t -= 128) < 128){ sel = 2; base = PK_FF1; }
    else if ((t -= 128) < 128){ sel = 3; base = PK_FF2; }
    else if ((t -= 128) < 128){ sel = 4; base = PK_E0; }
    else if ((t -= 128) < 320){ sel = 5; base = PK_E1; }
    else                      { t -= 320; sel = 6; base = PK_E2; }
    const int NKT = (sel == 5) ? 20 : 8;
    const int nt = t / NKT, kt = t % NKT;

    const int k = kt * 32 + (lane >> 1);
    const int n0 = nt * 16 + (lane & 1) * 8;
    const float* row;
    switch (sel) {
        case 0:  row = wqkv + (size_t)k * 768; break;
        case 1:  row = wout + (size_t)k * 256; break;
        case 2:  row = fw1  + (size_t)k * 256; break;
        case 3:  row = fw2  + (size_t)k * 256; break;
        case 4:  row = (k < 128) ? sp_w2 + (size_t)k * 256 : tok_w + (size_t)(k - 128) * 256; break;
        case 5:  row = (k < 512) ? te_w  + (size_t)k * 256 : tok_w + (size_t)(k - 512) * 256; break;
        default: row = (k < 128) ? poi_w + (size_t)k * 256 : tok_w + (size_t)(k - 128) * 256; break;
    }
    float4 v0 = *(const float4*)(row + n0);
    float4 v1 = *(const float4*)(row + n0 + 4);
    float* b = buf[wv];
    const int wb = (lane >> 1) * 17 + (lane & 1) * 8;
    b[wb + 0] = v0.x; b[wb + 1] = v0.y; b[wb + 2] = v0.z; b[wb + 3] = v0.w;
    b[wb + 4] = v1.x; b[wb + 5] = v1.y; b[wb + 6] = v1.z; b[wb + 7] = v1.w;
    __syncthreads();

    const int rb = (lane >> 4) * 8, c = lane & 15;
    frag8 fr;
#pragma unroll
    for (int j = 0; j < 8; ++j) fr[j] = (short)f2bf(b[(rb + j) * 17 + c]);
    *(frag8*)(pk + base + ((size_t)t * 64 + lane) * 8) = fr;
}

// ---------------- Kernel A: embed, N-split. 16 tokens x 64 cols per block, grid 1024 ----
// blockIdx: group g = bx>>2 (16 tokens), column-split ns = bx&3 (64 of 256 cols).
// M = 16 fully dense (no padded-row waste). Each wave owns one 16-col n-tile.
__global__ __launch_bounds__(256, 3)
void embed_mfma(const float* __restrict__ iq,
                const float* __restrict__ poi_coors,
                const float* __restrict__ poi_embed,
                const float* __restrict__ sp_w1, const float* __restrict__ sp_b1,
                const float* __restrict__ sp_b2,
                const float* __restrict__ four_w, const float* __restrict__ four_b,
                const float* __restrict__ te_b,
                const float* __restrict__ poi_ln_g, const float* __restrict__ poi_ln_b,
                const float* __restrict__ poi_b,
                const float* __restrict__ tok_emb,
                const float* __restrict__ tok_ln_g, const float* __restrict__ tok_ln_b,
                const float* __restrict__ tok_b,
                const unsigned short* __restrict__ pk,
                unsigned short* __restrict__ xout)
{
    constexpr int P0 = 264, P1 = 648, P2 = 264;   // bf16 pitches (16 valid rows)
    const int tid = threadIdx.x;
    const int w = tid >> 6, lane = tid & 63;
    const int quad = lane >> 4, l16 = lane & 15;
    const int g = blockIdx.x >> 2, ns = blockIdx.x & 3;
    const int n0 = g * TG;
    const int ntg = ns * 4 + w;                   // global n-tile this wave owns
    const int c0 = ntg * 16 + l16;                // global column (0..255)

    __shared__ __align__(16) short s_h0[16 * P0];   //  8448 B [hsp|t0n]
    __shared__ __align__(16) short s_h1[16 * P1];   // 20736 B [ht |t1n]
    __shared__ __align__(16) short s_h2[16 * P2];   //  8448 B [poin|t0n]
    __shared__ float s_meta[TG][6];
    __shared__ int   s_tok[TG][2];
    __shared__ float s_wd[4][4];
    __shared__ int   s_wi[4][4];
    __shared__ int   s_poi[TG];

    if (tid < TG) {
        const float* p = iq + (size_t)(n0 + tid) * 8;
        s_meta[tid][0] = p[0];
        s_meta[tid][1] = p[2];
        float ts = p[4];
        float dt = p[6];
        s_tok[tid][0] = (int)p[1];
        s_tok[tid][1] = (int)p[5];
        s_meta[tid][2] = fmodf(ts, 604800.0f) / 86400.0f;
        s_meta[tid][3] = fmodf(ts, 86400.0f) / 3600.0f;
        s_meta[tid][4] = fmodf(ts, 3600.0f) / 60.0f;
        s_meta[tid][5] = dt / 60.0f;
    }
    __syncthreads();

    // ---- POI argmin, 4 chunks of 4 tokens (register-light) ----
    for (int ch = 0; ch < 4; ++ch) {
        float sx[4], sy[4], bd[4];
        int bi[4];
#pragma unroll
        for (int t = 0; t < 4; ++t) {
            sx[t] = s_meta[ch * 4 + t][0]; sy[t] = s_meta[ch * 4 + t][1];
            bd[t] = INFINITY; bi[t] = NPOI;
        }
        const float2* pc = (const float2*)poi_coors;
        for (int i = tid; i < NPOI; i += 256) {
            float2 p = pc[i];
#pragma unroll
            for (int t = 0; t < 4; ++t) {
                float dx = __fsub_rn(p.x, sx[t]);
                float dy = __fsub_rn(p.y, sy[t]);
                float d  = __fadd_rn(__fmul_rn(dx, dx), __fmul_rn(dy, dy));
                if (d < bd[t]) { bd[t] = d; bi[t] = i; }   // ascending i -> first occurrence
            }
        }
#pragma unroll
        for (int m = 1; m < 64; m <<= 1) {
#pragma unroll
            for (int t = 0; t < 4; ++t) {
                float od = __shfl_xor(bd[t], m);
                int   oi = __shfl_xor(bi[t], m);
                if (od < bd[t] || (od == bd[t] && oi < bi[t])) { bd[t] = od; bi[t] = oi; }
            }
        }
        if (lane == 0) {
#pragma unroll
            for (int t = 0; t < 4; ++t) { s_wd[w][t] = bd[t]; s_wi[w][t] = bi[t]; }
        }
        __syncthreads();
        if (tid < 4) {
            float bdd = s_wd[0][tid]; int bii = s_wi[0][tid];
#pragma unroll
            for (int ww = 1; ww < 4; ++ww) {
                float od = s_wd[ww][tid]; int oi = s_wi[ww][tid];
                if (od < bdd || (od == bdd && oi < bii)) { bdd = od; bii = oi; }
            }
            s_poi[ch * 4 + tid] = bii;
        }
        __syncthreads();
    }

    // ---- wave w: LayerNorms for tokens w, w+4, w+8, w+12 ----
#pragma unroll
    for (int k4 = 0; k4 < 4; ++k4) {
        const int t = w + k4 * 4;
        ln128_bf(tok_emb + (size_t)s_tok[t][0] * E, tok_ln_g, tok_ln_b,
                 s_h0 + t * P0 + 128, s_h2 + t * P2 + 128, lane);
        ln128_bf(tok_emb + (size_t)s_tok[t][1] * E, tok_ln_g, tok_ln_b,
                 s_h1 + t * P1 + 512, nullptr, lane);
        ln128_bf(poi_embed + (size_t)s_poi[t] * E, poi_ln_g, poi_ln_b,
                 s_h2 + t * P2, nullptr, lane);
    }

    // ---- hsp (16x128), ht (16x512) ----
    for (int idx = tid; idx < TG * 128; idx += 256) {
        int t = idx >> 7, l = idx & 127;
        float h = s_meta[t][0] * sp_w1[l] + s_meta[t][1] * sp_w1[128 + l] + sp_b1[l];
        s_h0[t * P0 + l] = (short)f2bf((h >= 0.0f) ? h : 0.01f * h);
    }
    for (int idx = tid; idx < TG * 512; idx += 256) {
        int t = idx >> 9, jj = idx & 511, f = jj >> 7;
        float c = cosf(s_meta[t][2 + f] * four_w[jj] + four_b[jj]);
        s_h1[t * P1 + jj] = (short)f2bf((c >= 0.0f) ? c : 0.01f * c);
    }
    __syncthreads();

    // ---- MFMA passes: wave w owns 16 cols (n-tile ntg); all 16 rows valid ----
    // pass 0: h0 @ [sp_w2;tok_w]
    {
        float bv = sp_b2[c0] + tok_b[c0];
        f32x4 acc; acc[0] = bv; acc[1] = bv; acc[2] = bv; acc[3] = bv;
        for (int kt = 0; kt < 8; ++kt) {
            frag8 a = *(const frag8*)(&s_h0[l16 * P0 + kt * 32 + quad * 8]);
            frag8 b = *(const frag8*)(pk + PK_E0 + (((size_t)ntg * 8 + kt) * 64 + lane) * 8);
            acc = __builtin_amdgcn_mfma_f32_16x16x32_bf16(a, b, acc, 0, 0, 0);
        }
#pragma unroll
        for (int r = 0; r < 4; ++r)
            xout[(size_t)(n0 + quad * 4 + r) * 768 + c0] = f2bf(acc[r]);
    }
    // pass 1: h1 @ [te_w;tok_w]
    {
        float bv = te_b[c0] + tok_b[c0];
        f32x4 acc; acc[0] = bv; acc[1] = bv; acc[2] = bv; acc[3] = bv;
        for (int kt = 0; kt < 20; ++kt) {
            frag8 a = *(const frag8*)(&s_h1[l16 * P1 + kt * 32 + quad * 8]);
            frag8 b = *(const frag8*)(pk + PK_E1 + (((size_t)ntg * 20 + kt) * 64 + lane) * 8);
            acc = __builtin_amdgcn_mfma_f32_16x16x32_bf16(a, b, acc, 0, 0, 0);
        }
#pragma unroll
        for (int r = 0; r < 4; ++r)
            xout[(size_t)(n0 + quad * 4 + r) * 768 + 256 + c0] = f2bf(acc[r]);
    }
    // pass 2: h2 @ [poi_w;tok_w]
    {
        float bv = poi_b[c0] + tok_b[c0];
        f32x4 acc; acc[0] = bv; acc[1] = bv; acc[2] = bv; acc[3] = bv;
        for (int kt = 0; kt < 8; ++kt) {
            frag8 a = *(const frag8*)(&s_h2[l16 * P2 + kt * 32 + quad * 8]);
            frag8 b = *(const frag8*)(pk + PK_E2 + (((size_t)ntg * 8 + kt) * 64 + lane) * 8);
            acc = __builtin_amdgcn_mfma_f32_16x16x32_bf16(a, b, acc, 0, 0, 0);
        }
#pragma unroll
        for (int r = 0; r < 4; ++r)
            xout[(size_t)(n0 + quad * 4 + r) * 768 + 512 + c0] = f2bf(acc[r]);
    }
}

// ---------------- Kernel B: transformer, 4 tokens/block = 12 rows (padded 16) ----------------
__global__ __launch_bounds__(256, 3)
void mha_ff_mfma(const unsigned short* __restrict__ xin,   // bf16 (NTOK x 768)
                 const unsigned short* __restrict__ pk,
                 const float* __restrict__ bqkv, const float* __restrict__ bout,
                 const float* __restrict__ ln1g, const float* __restrict__ ln1b,
                 const float* __restrict__ fb1,  const float* __restrict__ fb2,
                 const float* __restrict__ ln2g, const float* __restrict__ ln2b,
                 const int* __restrict__ positions,
                 float* __restrict__ out)
{
    constexpr int PA = 264;   // bf16 pitch, A-operand region (16 rows)
    constexpr int PQ = 776;   // bf16 pitch, qkv region (16 rows)
    constexpr int PF = 260;   // fp32 pitch (16 rows)
    const int tid = threadIdx.x;
    const int w = tid >> 6, lane = tid & 63;
    const int quad = lane >> 4, l16 = lane & 15;
    const int n0tok = blockIdx.x * TB;
    const unsigned short* xg = xin + (size_t)n0tok * 3 * D;

    __shared__ __align__(16) short s_a[16 * PA];    // 8448 B: x -> o -> y
    __shared__ __align__(16) char  U[25088];        // qkv -> s_f|s_h
    __shared__ float s_att[TB * NH * 9];            // 288

    short* qkv = (short*)U;
    float* s_f = (float*)U;
    short* s_h = (short*)(U + 16640);

    // ---- stage x bf16 (12 rows x 256) -> s_a, direct 16B copies ----
    for (int i = tid; i < 12 * 32; i += 256) {       // 32 chunks of 8 elems per row
        int row = i >> 5, col = (i & 31) * 8;
        *(frag8*)(&s_a[row * PA + col]) = *(const frag8*)(xg + row * 256 + col);
    }
    __syncthreads();

    float xres[16];    // x residual at this thread's GEMM2 epilogue positions

    // ---- GEMM1: qkv = x @ Wqkv + bias (M=16 padded, N=768; wave w: 192 cols) ----
    {
        f32x4 acc[12];
#pragma unroll
        for (int nt = 0; nt < 12; ++nt) {
            float bv = bqkv[w * 192 + nt * 16 + l16];
            acc[nt][0] = bv; acc[nt][1] = bv; acc[nt][2] = bv; acc[nt][3] = bv;
        }
        for (int kt = 0; kt < 8; ++kt) {
            frag8 a = *(const frag8*)(&s_a[l16 * PA + kt * 32 + quad * 8]);
#pragma unroll
            for (int nt = 0; nt < 12; ++nt) {
                frag8 b = *(const frag8*)(pk + PK_QKV + (((size_t)(w * 12 + nt) * 8 + kt) * 64 + lane) * 8);
                acc[nt] = __builtin_amdgcn_mfma_f32_16x16x32_bf16(a, b, acc[nt], 0, 0, 0);
            }
        }
        // snapshot x residual before o overwrites s_a
#pragma unroll
        for (int nt = 0; nt < 4; ++nt)
#pragma unroll
            for (int r = 0; r < 4; ++r)
                xres[nt * 4 + r] = bf2f(s_a[(quad * 4 + r) * PA + w * 64 + nt * 16 + l16]);
#pragma unroll
        for (int nt = 0; nt < 12; ++nt)
#pragma unroll
            for (int r = 0; r < 4; ++r) {
                int row = quad * 4 + r, col = w * 192 + nt * 16 + l16;
                qkv[row * PQ + col] = (short)f2bf(acc[nt][r]);
            }
    }
    __syncthreads();

    // ---- attention scores + softmax fused: one triple per thread ----
    for (int idx3 = tid; idx3 < TB * NH * 3; idx3 += 256) {   // 96 triples
        int tok = idx3 / 24, rem = idx3 % 24;
        int h = rem / 3, qr = rem % 3;
        const short* qp = qkv + (tok * 3 + qr) * PQ + h * HD;
        const short* k0 = qkv + (tok * 3 + 0) * PQ + D + h * HD;
        const short* k1 = qkv + (tok * 3 + 1) * PQ + D + h * HD;
        const short* k2 = qkv + (tok * 3 + 2) * PQ + D + h * HD;
        float s0 = 0.0f, s1 = 0.0f, s2 = 0.0f;
#pragma unroll
        for (int u = 0; u < HD; ++u) {
            float q = bf2f(qp[u]);
            s0 += q * bf2f(k0[u]);
            s1 += q * bf2f(k1[u]);
            s2 += q * bf2f(k2[u]);
        }
        const float sc = 1.0f / sqrtf((float)HD);
        s0 *= sc; s1 *= sc; s2 *= sc;
        float m = fmaxf(s0, fmaxf(s1, s2));
        float e0 = expf(s0 - m), e1 = expf(s1 - m), e2 = expf(s2 - m);
        float inv = 1.0f / (e0 + e1 + e2);
        s_att[idx3 * 3 + 0] = e0 * inv;
        s_att[idx3 * 3 + 1] = e1 * inv;
        s_att[idx3 * 3 + 2] = e2 * inv;
    }
    __syncthreads();

    // ---- o = att @ v -> s_a bf16 (over x; residual snapshotted in regs) ----
    {
        const int h = tid >> 5;
#pragma unroll
        for (int tok = 0; tok < TB; ++tok) {
            float v0 = bf2f(qkv[(tok * 3 + 0) * PQ + 2 * D + tid]);
            float v1 = bf2f(qkv[(tok * 3 + 1) * PQ + 2 * D + tid]);
            float v2 = bf2f(qkv[(tok * 3 + 2) * PQ + 2 * D + tid]);
#pragma unroll
            for (int qr = 0; qr < 3; ++qr) {
                const float* a = s_att + tok * 72 + h * 9 + qr * 3;
                s_a[(tok * 3 + qr) * PA + tid] = (short)f2bf(a[0] * v0 + a[1] * v1 + a[2] * v2);
            }
        }
    }
    __syncthreads();   // qkv dead (scores + v consumed); o live in s_a

    // ---- GEMM2: proj = o @ Wout + bias + x -> s_f fp32 (over dead qkv) ----
    {
        f32x4 acc[4];
#pragma unroll
        for (int nt = 0; nt < 4; ++nt) {
            float bv = bout[w * 64 + nt * 16 + l16];
            acc[nt][0] = bv; acc[nt][1] = bv; acc[nt][2] = bv; acc[nt][3] = bv;
        }
        for (int kt = 0; kt < 8; ++kt) {
            frag8 a = *(const frag8*)(&s_a[l16 * PA + kt * 32 + quad * 8]);
#pragma unroll
            for (int nt = 0; nt < 4; ++nt) {
                frag8 b = *(const frag8*)(pk + PK_OUT + (((size_t)(w * 4 + nt) * 8 + kt) * 64 + lane) * 8);
                acc[nt] = __builtin_amdgcn_mfma_f32_16x16x32_bf16(a, b, acc[nt], 0, 0, 0);
            }
        }
        __syncthreads();   // all A-reads of o done before s_f overwrites qkv region
#pragma unroll
        for (int nt = 0; nt < 4; ++nt)
#pragma unroll
            for (int r = 0; r < 4; ++r) {
                int row = quad * 4 + r, col = w * 64 + nt * 16 + l16;
                s_f[row * PF + col] = acc[nt][r] + xres[nt * 4 + r];
            }
    }
    __syncthreads();

    // ---- LN1 (wave w: rows w, w+4, w+8, w+12) -> y fp32 in s_f, y bf16 -> s_a ----
#pragma unroll
    for (int rr = 0; rr < 4; ++rr) {
        int row = w + rr * 4, col = lane * 4;
        float4 v = *(const float4*)(&s_f[row * PF + col]);
        float mean = wsum64(v.x + v.y + v.z + v.w) * (1.0f / 256.0f);
        float dx = v.x - mean, dy = v.y - mean, dz = v.z - mean, dw = v.w - mean;
        float var = wsum64(dx * dx + dy * dy + dz * dz + dw * dw) * (1.0f / 256.0f);
        float s = sqrtf(var + LN_EPS);
        float4 g = *(const float4*)(ln1g + col), b = *(const float4*)(ln1b + col);
        float y0 = dx / s * g.x + b.x, y1 = dy / s * g.y + b.y;
        float y2 = dz / s * g.z + b.z, y3 = dw / s * g.w + b.w;
        float4 yv; yv.x = y0; yv.y = y1; yv.z = y2; yv.w = y3;
        *(float4*)(&s_f[row * PF + col]) = yv;
        ushort4 bb; bb.x = f2bf(y0); bb.y = f2bf(y1); bb.z = f2bf(y2); bb.w = f2bf(y3);
        *(ushort4*)(&s_a[row * PA + col]) = bb;
    }
    __syncthreads();

    // ---- FF1: h = relu(y @ FW1 + b1) -> s_h bf16 ----
    {
        f32x4 acc[4];
#pragma unroll
        for (int nt = 0; nt < 4; ++nt) {
            float bv = fb1[w * 64 + nt * 16 + l16];
            acc[nt][0] = bv; acc[nt][1] = bv; acc[nt][2] = bv; acc[nt][3] = bv;
        }
        for (int kt = 0; kt < 8; ++kt) {
            frag8 a = *(const frag8*)(&s_a[l16 * PA + kt * 32 + quad * 8]);
#pragma unroll
            for (int nt = 0; nt < 4; ++nt) {
                frag8 b = *(const frag8*)(pk + PK_FF1 + (((size_t)(w * 4 + nt) * 8 + kt) * 64 + lane) * 8);
                acc[nt] = __builtin_amdgcn_mfma_f32_16x16x32_bf16(a, b, acc[nt], 0, 0, 0);
            }
        }
#pragma unroll
        for (int nt = 0; nt < 4; ++nt)
#pragma unroll
            for (int r = 0; r < 4; ++r) {
                int row = quad * 4 + r, col = w * 64 + nt * 16 + l16;
                s_h[row * PA + col] = (short)f2bf(fmaxf(acc[nt][r], 0.0f));
            }
    }
    __syncthreads();

    // ---- FF2 + residual -> s_f (in place) ----
    {
        f32x4 acc[4];
#pragma unroll
        for (int nt = 0; nt < 4; ++nt) {
            float bv = fb2[w * 64 + nt * 16 + l16];
            acc[nt][0] = bv; acc[nt][1] = bv; acc[nt][2] = bv; acc[nt][3] = bv;
        }
        for (int kt = 0; kt < 8; ++kt) {
            frag8 a = *(const frag8*)(&s_h[l16 * PA + kt * 32 + quad * 8]);
#pragma unroll
            for (int nt = 0; nt < 4; ++nt) {
                frag8 b = *(const frag8*)(pk + PK_FF2 + (((size_t)(w * 4 + nt) * 8 + kt) * 64 + lane) * 8);
                acc[nt] = __builtin_amdgcn_mfma_f32_16x16x32_bf16(a, b, acc[nt], 0, 0, 0);
            }
        }
#pragma unroll
        for (int nt = 0; nt < 4; ++nt)
#pragma unroll
            for (int r = 0; r < 4; ++r) {
                int row = quad * 4 + r, col = w * 64 + nt * 16 + l16;
                float y = s_f[row * PF + col];   // same lane reads then writes
                s_f[row * PF + col] = acc[nt][r] + y;
            }
    }
    __syncthreads();

    // ---- LN2 (in place) ----
#pragma unroll
    for (int rr = 0; rr < 4; ++rr) {
        int row = w + rr * 4, col = lane * 4;
        float4 v = *(const float4*)(&s_f[row * PF + col]);
        float mean = wsum64(v.x + v.y + v.z + v.w) * (1.0f / 256.0f);
        float dx = v.x - mean, dy = v.y - mean, dz = v.z - mean, dw = v.w - mean;
        float var = wsum64(dx * dx + dy * dy + dz * dz + dw * dw) * (1.0f / 256.0f);
        float s = sqrtf(var + LN_EPS);
        float4 g = *(const float4*)(ln2g + col), b = *(const float4*)(ln2b + col);
        float4 zv;
        zv.x = dx / s * g.x + b.x; zv.y = dy / s * g.y + b.y;
        zv.z = dz / s * g.z + b.z; zv.w = dw / s * g.w + b.w;
        *(float4*)(&s_f[row * PF + col]) = zv;
    }
    __syncthreads();

    // ---- modality mean + positional encodings ----
    {
        const int fi = tid >> 1;
        const float freq = expf(-logf(10000.0f) * (2.0f * fi) / (float)D);
#pragma unroll
        for (int t = 0; t < TB; ++t) {
            int n = n0tok + t;
            float m3 = (s_f[(3 * t) * PF + tid] + s_f[(3 * t + 1) * PF + tid] +
                        s_f[(3 * t + 2) * PF + tid]) / 3.0f;
            float p0 = (float)positions[2 * n], p1 = (float)positions[2 * n + 1];
            float a0 = p0 * freq, a1 = p1 * freq;
            float pe = (tid & 1) ? (cosf(a0) + cosf(a1)) : (sinf(a0) + sinf(a1));
            out[(size_t)n * D + tid] = m3 + pe;
        }
    }
}

extern "C" void kernel_launch(void* const* d_in, const int* in_sizes, int n_in,
                              void* d_out, int out_size, void* d_ws, size_t ws_size,
                              hipStream_t stream)
{
    const float* iq        = (const float*)d_in[0];
    const int*   positions = (const int*)d_in[1];
    const float* poi_coors = (const float*)d_in[2];
    const float* poi_embed = (const float*)d_in[3];
    const float* sp_w1     = (const float*)d_in[4];
    const float* sp_b1     = (const float*)d_in[5];
    const float* sp_w2     = (const float*)d_in[6];
    const float* sp_b2     = (const float*)d_in[7];
    const float* four_w    = (const float*)d_in[8];
    const float* four_b    = (const float*)d_in[9];
    const float* te_w      = (const float*)d_in[10];
    const float* te_b      = (const float*)d_in[11];
    const float* poi_ln_g  = (const float*)d_in[12];
    const float* poi_ln_b  = (const float*)d_in[13];
    const float* poi_w     = (const float*)d_in[14];
    const float* poi_b     = (const float*)d_in[15];
    const float* tok_emb   = (const float*)d_in[16];
    const float* tok_ln_g  = (const float*)d_in[17];
    const float* tok_ln_b  = (const float*)d_in[18];
    const float* tok_w     = (const float*)d_in[19];
    const float* tok_b     = (const float*)d_in[20];
    const float* mha_in_w  = (const float*)d_in[21];
    const float* mha_in_b  = (const float*)d_in[22];
    const float* mha_out_w = (const float*)d_in[23];
    const float* mha_out_b = (const float*)d_in[24];
    const float* ln1_g     = (const float*)d_in[25];
    const float* ln1_b     = (const float*)d_in[26];
    const float* ff_w1     = (const float*)d_in[27];
    const float* ff_b1     = (const float*)d_in[28];
    const float* ff_w2     = (const float*)d_in[29];
    const float* ff_b2     = (const float*)d_in[30];
    const float* ln2_g     = (const float*)d_in[31];
    const float* ln2_b     = (const float*)d_in[32];

    unsigned short* pkw = (unsigned short*)d_ws;                     // 1.38 MB packed weights
    unsigned short* xws = (unsigned short*)((char*)d_ws + PK_TOTAL * 2);  // x bf16, 6.3 MB

    pack_weights<<<NTILES / 4, 256, 0, stream>>>(
        mha_in_w, mha_out_w, ff_w1, ff_w2, sp_w2, te_w, poi_w, tok_w, pkw);

    embed_mfma<<<(NTOK / TG) * 4, 256, 0, stream>>>(
        iq, poi_coors, poi_embed, sp_w1, sp_b1, sp_b2, four_w, four_b, te_b,
        poi_ln_g, poi_ln_b, poi_b, tok_emb, tok_ln_g, tok_ln_b, tok_b,
        pkw, xws);

    mha_ff_mfma<<<NTOK / TB, 256, 0, stream>>>(
        xws, pkw, mha_in_b, mha_out_b, ln1_g, ln1_b,
        ff_b1, ff_b2, ln2_g, ln2_b, positions, (float*)d_out);
}

// Round 13
// 220.694 us; speedup vs baseline: 1.0648x; 1.0648x over previous
//
#include <hip/hip_runtime.h>
#include <math.h>

namespace {
constexpr int E = 128, D = 256;
constexpr int NPOI = 10000, NH = 8, FFD = 256;
constexpr int HD = D / NH;            // 32
constexpr int NTOK = 4096;            // B*L
constexpr int TA = 4;                 // tokens/block, both kernels, grid 1024
constexpr float LN_EPS = 1e-5f;

// packed bf16 weight layout offsets (ushort elements)
constexpr int PK_QKV = 0;             // 48 nt x 8 kt x 512
constexpr int PK_OUT = 196608;        // 16 x 8 x 512
constexpr int PK_FF1 = 262144;
constexpr int PK_FF2 = 327680;
constexpr int PK_E0  = 393216;        // [sp_w2;tok_w]  K=256: 16 nt x 8 kt
constexpr int PK_E1  = 458752;        // [te_w;tok_w]   K=640: 16 nt x 20 kt
constexpr int PK_E2  = 622592;        // [poi_w;tok_w]  K=256: 16 nt x 8 kt
constexpr int PK_TOTAL = 688128;
constexpr int NTILES = PK_TOTAL / 512;   // 1344 tiles, 1 per wave, 336 blocks
}

using frag8 = __attribute__((ext_vector_type(8))) short;   // 8 bf16 (4 VGPRs)
using f32x4 = __attribute__((ext_vector_type(4))) float;   // 4 fp32 acc

__device__ __forceinline__ float bf2f(short s) {
    union { unsigned u; float f; } x; x.u = ((unsigned)(unsigned short)s) << 16; return x.f;
}
__device__ __forceinline__ unsigned short f2bf(float f) {
    union { float f; unsigned u; } x; x.f = f;
    unsigned r = x.u + 0x7fffu + ((x.u >> 16) & 1u);
    return (unsigned short)(r >> 16);
}

// 64-lane wave sum
__device__ __forceinline__ float wsum64(float v) {
#pragma unroll
    for (int m = 1; m < 64; m <<= 1) v += __shfl_xor(v, m);
    return v;
}

// LayerNorm of a 128-vector by one wave; bf16 store to dst1 (and dst2 if non-null)
__device__ __forceinline__ void ln128_bf(const float* __restrict__ src,
                                         const float* __restrict__ g,
                                         const float* __restrict__ b,
                                         short* __restrict__ dst1,
                                         short* __restrict__ dst2, int lane) {
    float v0 = src[lane], v1 = src[64 + lane];
    float mean = wsum64(v0 + v1) * (1.0f / 128.0f);
    float d0 = v0 - mean, d1 = v1 - mean;
    float var = wsum64(d0 * d0 + d1 * d1) * (1.0f / 128.0f);
    float inv = sqrtf(var + LN_EPS);
    float y0 = d0 / inv * g[lane] + b[lane];
    float y1 = d1 / inv * g[64 + lane] + b[64 + lane];
    unsigned short s0 = f2bf(y0), s1 = f2bf(y1);
    dst1[lane] = (short)s0; dst1[64 + lane] = (short)s1;
    if (dst2) { dst2[lane] = (short)s0; dst2[64 + lane] = (short)s1; }
}

// ---------------- Weight prepack: coalesced reads, LDS transpose ----------------
__global__ __launch_bounds__(256)
void pack_weights(const float* __restrict__ wqkv, const float* __restrict__ wout,
                  const float* __restrict__ fw1,  const float* __restrict__ fw2,
                  const float* __restrict__ sp_w2, const float* __restrict__ te_w,
                  const float* __restrict__ poi_w, const float* __restrict__ tok_w,
                  unsigned short* __restrict__ pk)
{
    __shared__ float buf[4][32 * 17];        // per-wave 544 floats
    const int wv = threadIdx.x >> 6, lane = threadIdx.x & 63;
    const int tile = blockIdx.x * 4 + wv;
    if (tile >= NTILES) return;              // exact fit: 336*4 = 1344

    int t = tile, sel, base;
    if (t < 384)              { sel = 0; base = PK_QKV; }
    else if ((t -= 384) < 128){ sel = 1; base = PK_OUT; }
    else if ((t -= 128) < 128){ sel = 2; base = PK_FF1; }
    else if ((t -= 128) < 128){ sel = 3; base = PK_FF2; }
    else if ((t -= 128) < 128){ sel = 4; base = PK_E0; }
    else if ((t -= 128) < 320){ sel = 5; base = PK_E1; }
    else                      { t -= 320; sel = 6; base = PK_E2; }
    const int NKT = (sel == 5) ? 20 : 8;
    const int nt = t / NKT, kt = t % NKT;

    const int k = kt * 32 + (lane >> 1);
    const int n0 = nt * 16 + (lane & 1) * 8;
    const float* row;
    switch (sel) {
        case 0:  row = wqkv + (size_t)k * 768; break;
        case 1:  row = wout + (size_t)k * 256; break;
        case 2:  row = fw1  + (size_t)k * 256; break;
        case 3:  row = fw2  + (size_t)k * 256; break;
        case 4:  row = (k < 128) ? sp_w2 + (size_t)k * 256 : tok_w + (size_t)(k - 128) * 256; break;
        case 5:  row = (k < 512) ? te_w  + (size_t)k * 256 : tok_w + (size_t)(k - 512) * 256; break;
        default: row = (k < 128) ? poi_w + (size_t)k * 256 : tok_w + (size_t)(k - 128) * 256; break;
    }
    float4 v0 = *(const float4*)(row + n0);
    float4 v1 = *(const float4*)(row + n0 + 4);
    float* b = buf[wv];
    const int wb = (lane >> 1) * 17 + (lane & 1) * 8;
    b[wb + 0] = v0.x; b[wb + 1] = v0.y; b[wb + 2] = v0.z; b[wb + 3] = v0.w;
    b[wb + 4] = v1.x; b[wb + 5] = v1.y; b[wb + 6] = v1.z; b[wb + 7] = v1.w;
    __syncthreads();

    const int rb = (lane >> 4) * 8, c = lane & 15;
    frag8 fr;
#pragma unroll
    for (int j = 0; j < 8; ++j) fr[j] = (short)f2bf(b[(rb + j) * 17 + c]);
    *(frag8*)(pk + base + ((size_t)t * 64 + lane) * 8) = fr;
}

// ---------------- Kernel A: embed -> x bf16 (NTOK x 768), 4 tokens/block ----------------
// launch_bounds (256,3): r11's (256,4) pinned VGPR at 64 -> ~24 MB scratch spill
// (WRITE_SIZE 30.7 MB vs 6.3 logical). 170-VGPR budget removes the spill.
__global__ __launch_bounds__(256, 3)
void embed_mfma(const float* __restrict__ iq,
                const float* __restrict__ poi_coors,
                const float* __restrict__ poi_embed,
                const float* __restrict__ sp_w1, const float* __restrict__ sp_b1,
                const float* __restrict__ sp_b2,
                const float* __restrict__ four_w, const float* __restrict__ four_b,
                const float* __restrict__ te_b,
                const float* __restrict__ poi_ln_g, const float* __restrict__ poi_ln_b,
                const float* __restrict__ poi_b,
                const float* __restrict__ tok_emb,
                const float* __restrict__ tok_ln_g, const float* __restrict__ tok_ln_b,
                const float* __restrict__ tok_b,
                const unsigned short* __restrict__ pk,
                unsigned short* __restrict__ xout)
{
    constexpr int P0 = 264, P1 = 648, P2 = 264;   // bf16 pitches
    const int tid = threadIdx.x;
    const int w = tid >> 6, lane = tid & 63;
    const int quad = lane >> 4, l16 = lane & 15;
    const int n0 = blockIdx.x * TA;

    __shared__ __align__(16) char  U[25088];       // overlapped h0|h1|h2 (garbage rows alias)
    __shared__ __align__(16) short s_x[TA * 768];  // 6144 B: staged x tile for coalesced write
    __shared__ float s_meta[TA][6];
    __shared__ int   s_tok[TA][2];
    __shared__ float s_wd[4][TA];
    __shared__ int   s_wi[4][TA];
    __shared__ int   s_poi[TA];

    short* h0 = (short*)U;                 // pitch 264, valid rows 0..3
    short* h1 = (short*)U + 1056;          // pitch 648, valid rows 0..3
    short* h2 = (short*)U + 3648;          // pitch 264, valid rows 0..3

    if (tid < TA) {
        const float* p = iq + (size_t)(n0 + tid) * 8;
        s_meta[tid][0] = p[0];
        s_meta[tid][1] = p[2];
        float ts = p[4];
        float dt = p[6];
        s_tok[tid][0] = (int)p[1];
        s_tok[tid][1] = (int)p[5];
        s_meta[tid][2] = fmodf(ts, 604800.0f) / 86400.0f;
        s_meta[tid][3] = fmodf(ts, 86400.0f) / 3600.0f;
        s_meta[tid][4] = fmodf(ts, 3600.0f) / 60.0f;
        s_meta[tid][5] = dt / 60.0f;
    }
    __syncthreads();

    // ---- POI argmin: one block-wide stride-256 scan for all 4 tokens ----
    {
        float sx[TA], sy[TA], bd[TA];
        int bi[TA];
#pragma unroll
        for (int t = 0; t < TA; ++t) {
            sx[t] = s_meta[t][0]; sy[t] = s_meta[t][1];
            bd[t] = INFINITY; bi[t] = NPOI;
        }
        const float2* pc = (const float2*)poi_coors;
        for (int i = tid; i < NPOI; i += 256) {
            float2 p = pc[i];
#pragma unroll
            for (int t = 0; t < TA; ++t) {
                float dx = __fsub_rn(p.x, sx[t]);
                float dy = __fsub_rn(p.y, sy[t]);
                float d  = __fadd_rn(__fmul_rn(dx, dx), __fmul_rn(dy, dy));
                if (d < bd[t]) { bd[t] = d; bi[t] = i; }   // ascending i -> first occurrence
            }
        }
#pragma unroll
        for (int m = 1; m < 64; m <<= 1) {
#pragma unroll
            for (int t = 0; t < TA; ++t) {
                float od = __shfl_xor(bd[t], m);
                int   oi = __shfl_xor(bi[t], m);
                if (od < bd[t] || (od == bd[t] && oi < bi[t])) { bd[t] = od; bi[t] = oi; }
            }
        }
        if (lane == 0) {
#pragma unroll
            for (int t = 0; t < TA; ++t) { s_wd[w][t] = bd[t]; s_wi[w][t] = bi[t]; }
        }
        __syncthreads();
        if (tid < TA) {
            float bdd = s_wd[0][tid]; int bii = s_wi[0][tid];
#pragma unroll
            for (int ww = 1; ww < 4; ++ww) {
                float od = s_wd[ww][tid]; int oi = s_wi[ww][tid];
                if (od < bdd || (od == bdd && oi < bii)) { bdd = od; bii = oi; }
            }
            s_poi[tid] = bii;
        }
        __syncthreads();
    }

    // ---- wave w: token w's three LayerNorms -> bf16 A-layout ----
    {
        const int t = w;
        ln128_bf(tok_emb + (size_t)s_tok[t][0] * E, tok_ln_g, tok_ln_b,
                 h0 + t * P0 + 128, h2 + t * P2 + 128, lane);
        ln128_bf(tok_emb + (size_t)s_tok[t][1] * E, tok_ln_g, tok_ln_b,
                 h1 + t * P1 + 512, nullptr, lane);
        ln128_bf(poi_embed + (size_t)s_poi[t] * E, poi_ln_g, poi_ln_b,
                 h2 + t * P2, nullptr, lane);
    }

    // ---- hsp (4x128), ht (4x512) ----
    for (int idx = tid; idx < TA * 128; idx += 256) {
        int t = idx >> 7, l = idx & 127;
        float h = s_meta[t][0] * sp_w1[l] + s_meta[t][1] * sp_w1[128 + l] + sp_b1[l];
        h0[t * P0 + l] = (short)f2bf((h >= 0.0f) ? h : 0.01f * h);
    }
    for (int idx = tid; idx < TA * 512; idx += 256) {
        int t = idx >> 9, jj = idx & 511, f = jj >> 7;
        float c = cosf(s_meta[t][2 + f] * four_w[jj] + four_b[jj]);
        h1[t * P1 + jj] = (short)f2bf((c >= 0.0f) ? c : 0.01f * c);
    }
    __syncthreads();

    // ---- MFMA passes: wave w covers cols [64w, 64w+64); quad==0 stages token rows ----
    // pass 0: h0 @ [sp_w2;tok_w] -> type 0
    {
        f32x4 acc[4];
#pragma unroll
        for (int nt = 0; nt < 4; ++nt) {
            int c = w * 64 + nt * 16 + l16;
            float bv = sp_b2[c] + tok_b[c];
            acc[nt][0] = bv; acc[nt][1] = bv; acc[nt][2] = bv; acc[nt][3] = bv;
        }
        for (int kt = 0; kt < 8; ++kt) {
            frag8 a = *(const frag8*)(&h0[l16 * P0 + kt * 32 + quad * 8]);
#pragma unroll
            for (int nt = 0; nt < 4; ++nt) {
                frag8 b = *(const frag8*)(pk + PK_E0 + (((size_t)(w * 4 + nt) * 8 + kt) * 64 + lane) * 8);
                acc[nt] = __builtin_amdgcn_mfma_f32_16x16x32_bf16(a, b, acc[nt], 0, 0, 0);
            }
        }
        if (quad == 0) {
#pragma unroll
            for (int nt = 0; nt < 4; ++nt)
#pragma unroll
                for (int r = 0; r < 4; ++r)
                    s_x[r * 768 + w * 64 + nt * 16 + l16] = (short)f2bf(acc[nt][r]);
        }
    }
    // pass 1: h1 @ [te_w;tok_w] -> type 1
    {
        f32x4 acc[4];
#pragma unroll
        for (int nt = 0; nt < 4; ++nt) {
            int c = w * 64 + nt * 16 + l16;
            float bv = te_b[c] + tok_b[c];
            acc[nt][0] = bv; acc[nt][1] = bv; acc[nt][2] = bv; acc[nt][3] = bv;
        }
        for (int kt = 0; kt < 20; ++kt) {
            frag8 a = *(const frag8*)(&h1[l16 * P1 + kt * 32 + quad * 8]);
#pragma unroll
            for (int nt = 0; nt < 4; ++nt) {
                frag8 b = *(const frag8*)(pk + PK_E1 + (((size_t)(w * 4 + nt) * 20 + kt) * 64 + lane) * 8);
                acc[nt] = __builtin_amdgcn_mfma_f32_16x16x32_bf16(a, b, acc[nt], 0, 0, 0);
            }
        }
        if (quad == 0) {
#pragma unroll
            for (int nt = 0; nt < 4; ++nt)
#pragma unroll
                for (int r = 0; r < 4; ++r)
                    s_x[r * 768 + 256 + w * 64 + nt * 16 + l16] = (short)f2bf(acc[nt][r]);
        }
    }
    // pass 2: h2 @ [poi_w;tok_w] -> type 2
    {
        f32x4 acc[4];
#pragma unroll
        for (int nt = 0; nt < 4; ++nt) {
            int c = w * 64 + nt * 16 + l16;
            float bv = poi_b[c] + tok_b[c];
            acc[nt][0] = bv; acc[nt][1] = bv; acc[nt][2] = bv; acc[nt][3] = bv;
        }
        for (int kt = 0; kt < 8; ++kt) {
            frag8 a = *(const frag8*)(&h2[l16 * P2 + kt * 32 + quad * 8]);
#pragma unroll
            for (int nt = 0; nt < 4; ++nt) {
                frag8 b = *(const frag8*)(pk + PK_E2 + (((size_t)(w * 4 + nt) * 8 + kt) * 64 + lane) * 8);
                acc[nt] = __builtin_amdgcn_mfma_f32_16x16x32_bf16(a, b, acc[nt], 0, 0, 0);
            }
        }
        if (quad == 0) {
#pragma unroll
            for (int nt = 0; nt < 4; ++nt)
#pragma unroll
                for (int r = 0; r < 4; ++r)
                    s_x[r * 768 + 512 + w * 64 + nt * 16 + l16] = (short)f2bf(acc[nt][r]);
        }
    }
    __syncthreads();

    // ---- coalesced 16B write-out: 384 contiguous frag8 chunks ----
    {
        unsigned short* xg = xout + (size_t)n0 * 768;
        for (int c = tid; c < TA * 96; c += 256)       // 96 chunks of 8 shorts per token row
            *(frag8*)(xg + c * 8) = *(const frag8*)(&s_x[c * 8]);
    }
}

// ---------------- Kernel B: transformer, 4 tokens/block = 12 rows (padded 16) ----------------
__global__ __launch_bounds__(256, 3)
void mha_ff_mfma(const unsigned short* __restrict__ xin,   // bf16 (NTOK x 768)
                 const unsigned short* __restrict__ pk,
                 const float* __restrict__ bqkv, const float* __restrict__ bout,
                 const float* __restrict__ ln1g, const float* __restrict__ ln1b,
                 const float* __restrict__ fb1,  const float* __restrict__ fb2,
                 const float* __restrict__ ln2g, const float* __restrict__ ln2b,
                 const int* __restrict__ positions,
                 float* __restrict__ out)
{
    constexpr int PA = 264;   // bf16 pitch, A-operand region (16 rows)
    constexpr int PQ = 776;   // bf16 pitch, qkv region (16 rows)
    constexpr int PF = 260;   // fp32 pitch (16 rows)
    const int tid = threadIdx.x;
    const int w = tid >> 6, lane = tid & 63;
    const int quad = lane >> 4, l16 = lane & 15;
    const int n0tok = blockIdx.x * TA;
    const unsigned short* xg = xin + (size_t)n0tok * 3 * D;

    __shared__ __align__(16) short s_a[16 * PA];    // 8448 B: x -> o -> y
    __shared__ __align__(16) char  U[25088];        // qkv -> s_f|s_h
    __shared__ float s_att[TA * NH * 9];            // 288

    short* qkv = (short*)U;
    float* s_f = (float*)U;
    short* s_h = (short*)(U + 16640);

    // ---- stage x bf16 (12 rows x 256) -> s_a, direct 16B copies ----
    for (int i = tid; i < 12 * 32; i += 256) {       // 32 chunks of 8 elems per row
        int row = i >> 5, col = (i & 31) * 8;
        *(frag8*)(&s_a[row * PA + col]) = *(const frag8*)(xg + row * 256 + col);
    }
    __syncthreads();

    float xres[16];    // x residual at this thread's GEMM2 epilogue positions

    // ---- GEMM1: qkv = x @ Wqkv + bias (M=16 padded, N=768; wave w: 192 cols) ----
    {
        f32x4 acc[12];
#pragma unroll
        for (int nt = 0; nt < 12; ++nt) {
            float bv = bqkv[w * 192 + nt * 16 + l16];
            acc[nt][0] = bv; acc[nt][1] = bv; acc[nt][2] = bv; acc[nt][3] = bv;
        }
        for (int kt = 0; kt < 8; ++kt) {
            frag8 a = *(const frag8*)(&s_a[l16 * PA + kt * 32 + quad * 8]);
#pragma unroll
            for (int nt = 0; nt < 12; ++nt) {
                frag8 b = *(const frag8*)(pk + PK_QKV + (((size_t)(w * 12 + nt) * 8 + kt) * 64 + lane) * 8);
                acc[nt] = __builtin_amdgcn_mfma_f32_16x16x32_bf16(a, b, acc[nt], 0, 0, 0);
            }
        }
        // snapshot x residual before o overwrites s_a
#pragma unroll
        for (int nt = 0; nt < 4; ++nt)
#pragma unroll
            for (int r = 0; r < 4; ++r)
                xres[nt * 4 + r] = bf2f(s_a[(quad * 4 + r) * PA + w * 64 + nt * 16 + l16]);
#pragma unroll
        for (int nt = 0; nt < 12; ++nt)
#pragma unroll
            for (int r = 0; r < 4; ++r) {
                int row = quad * 4 + r, col = w * 192 + nt * 16 + l16;
                qkv[row * PQ + col] = (short)f2bf(acc[nt][r]);
            }
    }
    __syncthreads();

    // ---- attention scores + softmax fused: one triple per thread ----
    for (int idx3 = tid; idx3 < TA * NH * 3; idx3 += 256) {   // 96 triples
        int tok = idx3 / 24, rem = idx3 % 24;
        int h = rem / 3, qr = rem % 3;
        const short* qp = qkv + (tok * 3 + qr) * PQ + h * HD;
        const short* k0 = qkv + (tok * 3 + 0) * PQ + D + h * HD;
        const short* k1 = qkv + (tok * 3 + 1) * PQ + D + h * HD;
        const short* k2 = qkv + (tok * 3 + 2) * PQ + D + h * HD;
        float s0 = 0.0f, s1 = 0.0f, s2 = 0.0f;
#pragma unroll
        for (int u = 0; u < HD; ++u) {
            float q = bf2f(qp[u]);
            s0 += q * bf2f(k0[u]);
            s1 += q * bf2f(k1[u]);
            s2 += q * bf2f(k2[u]);
        }
        const float sc = 1.0f / sqrtf((float)HD);
        s0 *= sc; s1 *= sc; s2 *= sc;
        float m = fmaxf(s0, fmaxf(s1, s2));
        float e0 = expf(s0 - m), e1 = expf(s1 - m), e2 = expf(s2 - m);
        float inv = 1.0f / (e0 + e1 + e2);
        s_att[idx3 * 3 + 0] = e0 * inv;
        s_att[idx3 * 3 + 1] = e1 * inv;
        s_att[idx3 * 3 + 2] = e2 * inv;
    }
    __syncthreads();

    // ---- o = att @ v -> s_a bf16 (over x; residual snapshotted in regs) ----
    {
        const int h = tid >> 5;
#pragma unroll
        for (int tok = 0; tok < TA; ++tok) {
            float v0 = bf2f(qkv[(tok * 3 + 0) * PQ + 2 * D + tid]);
            float v1 = bf2f(qkv[(tok * 3 + 1) * PQ + 2 * D + tid]);
            float v2 = bf2f(qkv[(tok * 3 + 2) * PQ + 2 * D + tid]);
#pragma unroll
            for (int qr = 0; qr < 3; ++qr) {
                const float* a = s_att + tok * 72 + h * 9 + qr * 3;
                s_a[(tok * 3 + qr) * PA + tid] = (short)f2bf(a[0] * v0 + a[1] * v1 + a[2] * v2);
            }
        }
    }
    __syncthreads();   // qkv dead (scores + v consumed); o live in s_a

    // ---- GEMM2: proj = o @ Wout + bias + x -> s_f fp32 (over dead qkv) ----
    {
        f32x4 acc[4];
#pragma unroll
        for (int nt = 0; nt < 4; ++nt) {
            float bv = bout[w * 64 + nt * 16 + l16];
            acc[nt][0] = bv; acc[nt][1] = bv; acc[nt][2] = bv; acc[nt][3] = bv;
        }
        for (int kt = 0; kt < 8; ++kt) {
            frag8 a = *(const frag8*)(&s_a[l16 * PA + kt * 32 + quad * 8]);
#pragma unroll
            for (int nt = 0; nt < 4; ++nt) {
                frag8 b = *(const frag8*)(pk + PK_OUT + (((size_t)(w * 4 + nt) * 8 + kt) * 64 + lane) * 8);
                acc[nt] = __builtin_amdgcn_mfma_f32_16x16x32_bf16(a, b, acc[nt], 0, 0, 0);
            }
        }
        __syncthreads();   // all A-reads of o done before s_f overwrites qkv region
#pragma unroll
        for (int nt = 0; nt < 4; ++nt)
#pragma unroll
            for (int r = 0; r < 4; ++r) {
                int row = quad * 4 + r, col = w * 64 + nt * 16 + l16;
                s_f[row * PF + col] = acc[nt][r] + xres[nt * 4 + r];
            }
    }
    __syncthreads();

    // ---- LN1 (wave w: rows w, w+4, w+8, w+12) -> y fp32 in s_f, y bf16 -> s_a ----
#pragma unroll
    for (int rr = 0; rr < 4; ++rr) {
        int row = w + rr * 4, col = lane * 4;
        float4 v = *(const float4*)(&s_f[row * PF + col]);
        float mean = wsum64(v.x + v.y + v.z + v.w) * (1.0f / 256.0f);
        float dx = v.x - mean, dy = v.y - mean, dz = v.z - mean, dw = v.w - mean;
        float var = wsum64(dx * dx + dy * dy + dz * dz + dw * dw) * (1.0f / 256.0f);
        float s = sqrtf(var + LN_EPS);
        float4 g = *(const float4*)(ln1g + col), b = *(const float4*)(ln1b + col);
        float y0 = dx / s * g.x + b.x, y1 = dy / s * g.y + b.y;
        float y2 = dz / s * g.z + b.z, y3 = dw / s * g.w + b.w;
        float4 yv; yv.x = y0; yv.y = y1; yv.z = y2; yv.w = y3;
        *(float4*)(&s_f[row * PF + col]) = yv;
        ushort4 bb; bb.x = f2bf(y0); bb.y = f2bf(y1); bb.z = f2bf(y2); bb.w = f2bf(y3);
        *(ushort4*)(&s_a[row * PA + col]) = bb;
    }
    __syncthreads();

    // ---- FF1: h = relu(y @ FW1 + b1) -> s_h bf16 ----
    {
        f32x4 acc[4];
#pragma unroll
        for (int nt = 0; nt < 4; ++nt) {
            float bv = fb1[w * 64 + nt * 16 + l16];
            acc[nt][0] = bv; acc[nt][1] = bv; acc[nt][2] = bv; acc[nt][3] = bv;
        }
        for (int kt = 0; kt < 8; ++kt) {
            frag8 a = *(const frag8*)(&s_a[l16 * PA + kt * 32 + quad * 8]);
#pragma unroll
            for (int nt = 0; nt < 4; ++nt) {
                frag8 b = *(const frag8*)(pk + PK_FF1 + (((size_t)(w * 4 + nt) * 8 + kt) * 64 + lane) * 8);
                acc[nt] = __builtin_amdgcn_mfma_f32_16x16x32_bf16(a, b, acc[nt], 0, 0, 0);
            }
        }
#pragma unroll
        for (int nt = 0; nt < 4; ++nt)
#pragma unroll
            for (int r = 0; r < 4; ++r) {
                int row = quad * 4 + r, col = w * 64 + nt * 16 + l16;
                s_h[row * PA + col] = (short)f2bf(fmaxf(acc[nt][r], 0.0f));
            }
    }
    __syncthreads();

    // ---- FF2 + residual -> s_f (in place) ----
    {
        f32x4 acc[4];
#pragma unroll
        for (int nt = 0; nt < 4; ++nt) {
            float bv = fb2[w * 64 + nt * 16 + l16];
            acc[nt][0] = bv; acc[nt][1] = bv; acc[nt][2] = bv; acc[nt][3] = bv;
        }
        for (int kt = 0; kt < 8; ++kt) {
            frag8 a = *(const frag8*)(&s_h[l16 * PA + kt * 32 + quad * 8]);
#pragma unroll
            for (int nt = 0; nt < 4; ++nt) {
                frag8 b = *(const frag8*)(pk + PK_FF2 + (((size_t)(w * 4 + nt) * 8 + kt) * 64 + lane) * 8);
                acc[nt] = __builtin_amdgcn_mfma_f32_16x16x32_bf16(a, b, acc[nt], 0, 0, 0);
            }
        }
#pragma unroll
        for (int nt = 0; nt < 4; ++nt)
#pragma unroll
            for (int r = 0; r < 4; ++r) {
                int row = quad * 4 + r, col = w * 64 + nt * 16 + l16;
                float y = s_f[row * PF + col];   // same lane reads then writes
                s_f[row * PF + col] = acc[nt][r] + y;
            }
    }
    __syncthreads();

    // ---- LN2 (in place) ----
#pragma unroll
    for (int rr = 0; rr < 4; ++rr) {
        int row = w + rr * 4, col = lane * 4;
        float4 v = *(const float4*)(&s_f[row * PF + col]);
        float mean = wsum64(v.x + v.y + v.z + v.w) * (1.0f / 256.0f);
        float dx = v.x - mean, dy = v.y - mean, dz = v.z - mean, dw = v.w - mean;
        float var = wsum64(dx * dx + dy * dy + dz * dz + dw * dw) * (1.0f / 256.0f);
        float s = sqrtf(var + LN_EPS);
        float4 g = *(const float4*)(ln2g + col), b = *(const float4*)(ln2b + col);
        float4 zv;
        zv.x = dx / s * g.x + b.x; zv.y = dy / s * g.y + b.y;
        zv.z = dz / s * g.z + b.z; zv.w = dw / s * g.w + b.w;
        *(float4*)(&s_f[row * PF + col]) = zv;
    }
    __syncthreads();

    // ---- modality mean + positional encodings ----
    {
        const int fi = tid >> 1;
        const float freq = expf(-logf(10000.0f) * (2.0f * fi) / (float)D);
#pragma unroll
        for (int t = 0; t < TA; ++t) {
            int n = n0tok + t;
            float m3 = (s_f[(3 * t) * PF + tid] + s_f[(3 * t + 1) * PF + tid] +
                        s_f[(3 * t + 2) * PF + tid]) / 3.0f;
            float p0 = (float)positions[2 * n], p1 = (float)positions[2 * n + 1];
            float a0 = p0 * freq, a1 = p1 * freq;
            float pe = (tid & 1) ? (cosf(a0) + cosf(a1)) : (sinf(a0) + sinf(a1));
            out[(size_t)n * D + tid] = m3 + pe;
        }
    }
}

extern "C" void kernel_launch(void* const* d_in, const int* in_sizes, int n_in,
                              void* d_out, int out_size, void* d_ws, size_t ws_size,
                              hipStream_t stream)
{
    const float* iq        = (const float*)d_in[0];
    const int*   positions = (const int*)d_in[1];
    const float* poi_coors = (const float*)d_in[2];
    const float* poi_embed = (const float*)d_in[3];
    const float* sp_w1     = (const float*)d_in[4];
    const float* sp_b1     = (const float*)d_in[5];
    const float* sp_w2     = (const float*)d_in[6];
    const float* sp_b2     = (const float*)d_in[7];
    const float* four_w    = (const float*)d_in[8];
    const float* four_b    = (const float*)d_in[9];
    const float* te_w      = (const float*)d_in[10];
    const float* te_b      = (const float*)d_in[11];
    const float* poi_ln_g  = (const float*)d_in[12];
    const float* poi_ln_b  = (const float*)d_in[13];
    const float* poi_w     = (const float*)d_in[14];
    const float* poi_b     = (const float*)d_in[15];
    const float* tok_emb   = (const float*)d_in[16];
    const float* tok_ln_g  = (const float*)d_in[17];
    const float* tok_ln_b  = (const float*)d_in[18];
    const float* tok_w     = (const float*)d_in[19];
    const float* tok_b     = (const float*)d_in[20];
    const float* mha_in_w  = (const float*)d_in[21];
    const float* mha_in_b  = (const float*)d_in[22];
    const float* mha_out_w = (const float*)d_in[23];
    const float* mha_out_b = (const float*)d_in[24];
    const float* ln1_g     = (const float*)d_in[25];
    const float* ln1_b     = (const float*)d_in[26];
    const float* ff_w1     = (const float*)d_in[27];
    const float* ff_b1     = (const float*)d_in[28];
    const float* ff_w2     = (const float*)d_in[29];
    const float* ff_b2     = (const float*)d_in[30];
    const float* ln2_g     = (const float*)d_in[31];
    const float* ln2_b     = (const float*)d_in[32];

    unsigned short* pkw = (unsigned short*)d_ws;                     // 1.38 MB packed weights
    unsigned short* xws = (unsigned short*)((char*)d_ws + PK_TOTAL * 2);  // x bf16, 6.3 MB

    pack_weights<<<NTILES / 4, 256, 0, stream>>>(
        mha_in_w, mha_out_w, ff_w1, ff_w2, sp_w2, te_w, poi_w, tok_w, pkw);

    embed_mfma<<<NTOK / TA, 256, 0, stream>>>(
        iq, poi_coors, poi_embed, sp_w1, sp_b1, sp_b2, four_w, four_b, te_b,
        poi_ln_g, poi_ln_b, poi_b, tok_emb, tok_ln_g, tok_ln_b, tok_b,
        pkw, xws);

    mha_ff_mfma<<<NTOK / TA, 256, 0, stream>>>(
        xws, pkw, mha_in_b, mha_out_b, ln1_g, ln1_b,
        ff_b1, ff_b2, ln2_g, ln2_b, positions, (float*)d_out);
}

// Round 14
// 202.740 us; speedup vs baseline: 1.1591x; 1.0886x over previous
//
#include <hip/hip_runtime.h>
#include <math.h>

namespace {
constexpr int E = 128, D = 256;
constexpr int NPOI = 10000, NH = 8, FFD = 256;
constexpr int HD = D / NH;            // 32
constexpr int NTOK = 4096;            // B*L
constexpr int TA = 8;                 // tokens/block, embed kernel, grid 512
constexpr int TB = 4;                 // tokens/block, mha kernel, grid 1024
constexpr float LN_EPS = 1e-5f;

// packed bf16 weight layout offsets (ushort elements)
constexpr int PK_QKV = 0;             // 48 nt x 8 kt x 512
constexpr int PK_OUT = 196608;        // 16 x 8 x 512
constexpr int PK_FF1 = 262144;
constexpr int PK_FF2 = 327680;
constexpr int PK_E0  = 393216;        // [sp_w2;tok_w]  K=256: 16 nt x 8 kt
constexpr int PK_E1  = 458752;        // [te_w;tok_w]   K=640: 16 nt x 20 kt
constexpr int PK_E2  = 622592;        // [poi_w;tok_w]  K=256: 16 nt x 8 kt
constexpr int PK_TOTAL = 688128;
constexpr int NTILES = PK_TOTAL / 512;   // 1344 tiles, 1 per wave, 336 blocks
}

using frag8 = __attribute__((ext_vector_type(8))) short;   // 8 bf16 (4 VGPRs)
using f32x4 = __attribute__((ext_vector_type(4))) float;   // 4 fp32 acc

__device__ __forceinline__ float bf2f(short s) {
    union { unsigned u; float f; } x; x.u = ((unsigned)(unsigned short)s) << 16; return x.f;
}
__device__ __forceinline__ unsigned short f2bf(float f) {
    union { float f; unsigned u; } x; x.f = f;
    unsigned r = x.u + 0x7fffu + ((x.u >> 16) & 1u);
    return (unsigned short)(r >> 16);
}

// 64-lane wave sum
__device__ __forceinline__ float wsum64(float v) {
#pragma unroll
    for (int m = 1; m < 64; m <<= 1) v += __shfl_xor(v, m);
    return v;
}

// LayerNorm of a 128-vector by one wave; bf16 store to dst1 (and dst2 if non-null)
__device__ __forceinline__ void ln128_bf(const float* __restrict__ src,
                                         const float* __restrict__ g,
                                         const float* __restrict__ b,
                                         short* __restrict__ dst1,
                                         short* __restrict__ dst2, int lane) {
    float v0 = src[lane], v1 = src[64 + lane];
    float mean = wsum64(v0 + v1) * (1.0f / 128.0f);
    float d0 = v0 - mean, d1 = v1 - mean;
    float var = wsum64(d0 * d0 + d1 * d1) * (1.0f / 128.0f);
    float inv = sqrtf(var + LN_EPS);
    float y0 = d0 / inv * g[lane] + b[lane];
    float y1 = d1 / inv * g[64 + lane] + b[64 + lane];
    unsigned short s0 = f2bf(y0), s1 = f2bf(y1);
    dst1[lane] = (short)s0; dst1[64 + lane] = (short)s1;
    if (dst2) { dst2[lane] = (short)s0; dst2[64 + lane] = (short)s1; }
}

// ---------------- Weight prepack: coalesced reads, LDS transpose ----------------
__global__ __launch_bounds__(256)
void pack_weights(const float* __restrict__ wqkv, const float* __restrict__ wout,
                  const float* __restrict__ fw1,  const float* __restrict__ fw2,
                  const float* __restrict__ sp_w2, const float* __restrict__ te_w,
                  const float* __restrict__ poi_w, const float* __restrict__ tok_w,
                  unsigned short* __restrict__ pk)
{
    __shared__ float buf[4][32 * 17];        // per-wave 544 floats
    const int wv = threadIdx.x >> 6, lane = threadIdx.x & 63;
    const int tile = blockIdx.x * 4 + wv;
    if (tile >= NTILES) return;              // exact fit: 336*4 = 1344

    int t = tile, sel, base;
    if (t < 384)              { sel = 0; base = PK_QKV; }
    else if ((t -= 384) < 128){ sel = 1; base = PK_OUT; }
    else if ((t -= 128) < 128){ sel = 2; base = PK_FF1; }
    else if ((t -= 128) < 128){ sel = 3; base = PK_FF2; }
    else if ((t -= 128) < 128){ sel = 4; base = PK_E0; }
    else if ((t -= 128) < 320){ sel = 5; base = PK_E1; }
    else                      { t -= 320; sel = 6; base = PK_E2; }
    const int NKT = (sel == 5) ? 20 : 8;
    const int nt = t / NKT, kt = t % NKT;

    const int k = kt * 32 + (lane >> 1);
    const int n0 = nt * 16 + (lane & 1) * 8;
    const float* row;
    switch (sel) {
        case 0:  row = wqkv + (size_t)k * 768; break;
        case 1:  row = wout + (size_t)k * 256; break;
        case 2:  row = fw1  + (size_t)k * 256; break;
        case 3:  row = fw2  + (size_t)k * 256; break;
        case 4:  row = (k < 128) ? sp_w2 + (size_t)k * 256 : tok_w + (size_t)(k - 128) * 256; break;
        case 5:  row = (k < 512) ? te_w  + (size_t)k * 256 : tok_w + (size_t)(k - 512) * 256; break;
        default: row = (k < 128) ? poi_w + (size_t)k * 256 : tok_w + (size_t)(k - 128) * 256; break;
    }
    float4 v0 = *(const float4*)(row + n0);
    float4 v1 = *(const float4*)(row + n0 + 4);
    float* b = buf[wv];
    const int wb = (lane >> 1) * 17 + (lane & 1) * 8;
    b[wb + 0] = v0.x; b[wb + 1] = v0.y; b[wb + 2] = v0.z; b[wb + 3] = v0.w;
    b[wb + 4] = v1.x; b[wb + 5] = v1.y; b[wb + 6] = v1.z; b[wb + 7] = v1.w;
    __syncthreads();

    const int rb = (lane >> 4) * 8, c = lane & 15;
    frag8 fr;
#pragma unroll
    for (int j = 0; j < 8; ++j) fr[j] = (short)f2bf(b[(rb + j) * 17 + c]);
    *(frag8*)(pk + base + ((size_t)t * 64 + lane) * 8) = fr;
}

// ---------------- Kernel A: embed -> x bf16, 8 tokens/block, grid 512 ----------------
// TA=8: M-tiles carry 8 valid rows of 16 (2x MFMA waste vs r13's 4x), per-token
// weight streaming and prep both halve. Overlapped h-buffers keep LDS ~38 KB.
__global__ __launch_bounds__(256, 2)
void embed_mfma(const float* __restrict__ iq,
                const float* __restrict__ poi_coors,
                const float* __restrict__ poi_embed,
                const float* __restrict__ sp_w1, const float* __restrict__ sp_b1,
                const float* __restrict__ sp_b2,
                const float* __restrict__ four_w, const float* __restrict__ four_b,
                const float* __restrict__ te_b,
                const float* __restrict__ poi_ln_g, const float* __restrict__ poi_ln_b,
                const float* __restrict__ poi_b,
                const float* __restrict__ tok_emb,
                const float* __restrict__ tok_ln_g, const float* __restrict__ tok_ln_b,
                const float* __restrict__ tok_b,
                const unsigned short* __restrict__ pk,
                unsigned short* __restrict__ xout)
{
    constexpr int P0 = 264, P1 = 648, P2 = 264;   // bf16 pitches
    const int tid = threadIdx.x;
    const int w = tid >> 6, lane = tid & 63;
    const int quad = lane >> 4, l16 = lane & 15;
    const int n0 = blockIdx.x * TA;

    // Overlapped h-buffers: valid rows 0..7 each; garbage rows alias neighbors.
    // h0 @0 (8x264), h1 @2112 (8x648), h2 @7296 (8x264); reads reach 12472 elems.
    __shared__ __align__(16) short U[12544];        // 25088 B
    __shared__ __align__(16) short s_x[TA * 768];   // 12288 B staged x
    __shared__ float s_meta[TA][6];
    __shared__ int   s_tok[TA][2];
    __shared__ float s_wd[4][TA];
    __shared__ int   s_wi[4][TA];
    __shared__ int   s_poi[TA];

    short* h0 = U;
    short* h1 = U + 2112;
    short* h2 = U + 7296;

    if (tid < TA) {
        const float* p = iq + (size_t)(n0 + tid) * 8;
        s_meta[tid][0] = p[0];
        s_meta[tid][1] = p[2];
        float ts = p[4];
        float dt = p[6];
        s_tok[tid][0] = (int)p[1];
        s_tok[tid][1] = (int)p[5];
        s_meta[tid][2] = fmodf(ts, 604800.0f) / 86400.0f;
        s_meta[tid][3] = fmodf(ts, 86400.0f) / 3600.0f;
        s_meta[tid][4] = fmodf(ts, 3600.0f) / 60.0f;
        s_meta[tid][5] = dt / 60.0f;
    }
    __syncthreads();

    // ---- POI argmin: one block-wide stride-256 scan for all 8 tokens ----
    {
        float sx[TA], sy[TA], bd[TA];
        int bi[TA];
#pragma unroll
        for (int t = 0; t < TA; ++t) {
            sx[t] = s_meta[t][0]; sy[t] = s_meta[t][1];
            bd[t] = INFINITY; bi[t] = NPOI;
        }
        const float2* pc = (const float2*)poi_coors;
        for (int i = tid; i < NPOI; i += 256) {
            float2 p = pc[i];
#pragma unroll
            for (int t = 0; t < TA; ++t) {
                float dx = __fsub_rn(p.x, sx[t]);
                float dy = __fsub_rn(p.y, sy[t]);
                float d  = __fadd_rn(__fmul_rn(dx, dx), __fmul_rn(dy, dy));
                if (d < bd[t]) { bd[t] = d; bi[t] = i; }   // ascending i -> first occurrence
            }
        }
#pragma unroll
        for (int m = 1; m < 64; m <<= 1) {
#pragma unroll
            for (int t = 0; t < TA; ++t) {
                float od = __shfl_xor(bd[t], m);
                int   oi = __shfl_xor(bi[t], m);
                if (od < bd[t] || (od == bd[t] && oi < bi[t])) { bd[t] = od; bi[t] = oi; }
            }
        }
        if (lane == 0) {
#pragma unroll
            for (int t = 0; t < TA; ++t) { s_wd[w][t] = bd[t]; s_wi[w][t] = bi[t]; }
        }
        __syncthreads();
        if (tid < TA) {
            float bdd = s_wd[0][tid]; int bii = s_wi[0][tid];
#pragma unroll
            for (int ww = 1; ww < 4; ++ww) {
                float od = s_wd[ww][tid]; int oi = s_wi[ww][tid];
                if (od < bdd || (od == bdd && oi < bii)) { bdd = od; bii = oi; }
            }
            s_poi[tid] = bii;
        }
        __syncthreads();
    }

    // ---- wave w: LayerNorms for tokens w and w+4 ----
#pragma unroll
    for (int k2 = 0; k2 < 2; ++k2) {
        const int t = w + k2 * 4;
        ln128_bf(tok_emb + (size_t)s_tok[t][0] * E, tok_ln_g, tok_ln_b,
                 h0 + t * P0 + 128, h2 + t * P2 + 128, lane);
        ln128_bf(tok_emb + (size_t)s_tok[t][1] * E, tok_ln_g, tok_ln_b,
                 h1 + t * P1 + 512, nullptr, lane);
        ln128_bf(poi_embed + (size_t)s_poi[t] * E, poi_ln_g, poi_ln_b,
                 h2 + t * P2, nullptr, lane);
    }

    // ---- hsp (8x128), ht (8x512) ----
    for (int idx = tid; idx < TA * 128; idx += 256) {
        int t = idx >> 7, l = idx & 127;
        float h = s_meta[t][0] * sp_w1[l] + s_meta[t][1] * sp_w1[128 + l] + sp_b1[l];
        h0[t * P0 + l] = (short)f2bf((h >= 0.0f) ? h : 0.01f * h);
    }
    for (int idx = tid; idx < TA * 512; idx += 256) {
        int t = idx >> 9, jj = idx & 511, f = jj >> 7;
        float c = cosf(s_meta[t][2 + f] * four_w[jj] + four_b[jj]);
        h1[t * P1 + jj] = (short)f2bf((c >= 0.0f) ? c : 0.01f * c);
    }
    __syncthreads();

    // ---- MFMA passes: wave w covers cols [64w,64w+64); rows 0..7 valid (quad<2) ----
    // pass 0: h0 @ [sp_w2;tok_w] -> type 0
    {
        f32x4 acc[4];
#pragma unroll
        for (int nt = 0; nt < 4; ++nt) {
            int c = w * 64 + nt * 16 + l16;
            float bv = sp_b2[c] + tok_b[c];
            acc[nt][0] = bv; acc[nt][1] = bv; acc[nt][2] = bv; acc[nt][3] = bv;
        }
        for (int kt = 0; kt < 8; ++kt) {
            frag8 a = *(const frag8*)(&h0[l16 * P0 + kt * 32 + quad * 8]);
#pragma unroll
            for (int nt = 0; nt < 4; ++nt) {
                frag8 b = *(const frag8*)(pk + PK_E0 + (((size_t)(w * 4 + nt) * 8 + kt) * 64 + lane) * 8);
                acc[nt] = __builtin_amdgcn_mfma_f32_16x16x32_bf16(a, b, acc[nt], 0, 0, 0);
            }
        }
        if (quad < 2) {
#pragma unroll
            for (int nt = 0; nt < 4; ++nt)
#pragma unroll
                for (int r = 0; r < 4; ++r)
                    s_x[(quad * 4 + r) * 768 + w * 64 + nt * 16 + l16] = (short)f2bf(acc[nt][r]);
        }
    }
    // pass 1: h1 @ [te_w;tok_w] -> type 1
    {
        f32x4 acc[4];
#pragma unroll
        for (int nt = 0; nt < 4; ++nt) {
            int c = w * 64 + nt * 16 + l16;
            float bv = te_b[c] + tok_b[c];
            acc[nt][0] = bv; acc[nt][1] = bv; acc[nt][2] = bv; acc[nt][3] = bv;
        }
        for (int kt = 0; kt < 20; ++kt) {
            frag8 a = *(const frag8*)(&h1[l16 * P1 + kt * 32 + quad * 8]);
#pragma unroll
            for (int nt = 0; nt < 4; ++nt) {
                frag8 b = *(const frag8*)(pk + PK_E1 + (((size_t)(w * 4 + nt) * 20 + kt) * 64 + lane) * 8);
                acc[nt] = __builtin_amdgcn_mfma_f32_16x16x32_bf16(a, b, acc[nt], 0, 0, 0);
            }
        }
        if (quad < 2) {
#pragma unroll
            for (int nt = 0; nt < 4; ++nt)
#pragma unroll
                for (int r = 0; r < 4; ++r)
                    s_x[(quad * 4 + r) * 768 + 256 + w * 64 + nt * 16 + l16] = (short)f2bf(acc[nt][r]);
        }
    }
    // pass 2: h2 @ [poi_w;tok_w] -> type 2
    {
        f32x4 acc[4];
#pragma unroll
        for (int nt = 0; nt < 4; ++nt) {
            int c = w * 64 + nt * 16 + l16;
            float bv = poi_b[c] + tok_b[c];
            acc[nt][0] = bv; acc[nt][1] = bv; acc[nt][2] = bv; acc[nt][3] = bv;
        }
        for (int kt = 0; kt < 8; ++kt) {
            frag8 a = *(const frag8*)(&h2[l16 * P2 + kt * 32 + quad * 8]);
#pragma unroll
            for (int nt = 0; nt < 4; ++nt) {
                frag8 b = *(const frag8*)(pk + PK_E2 + (((size_t)(w * 4 + nt) * 8 + kt) * 64 + lane) * 8);
                acc[nt] = __builtin_amdgcn_mfma_f32_16x16x32_bf16(a, b, acc[nt], 0, 0, 0);
            }
        }
        if (quad < 2) {
#pragma unroll
            for (int nt = 0; nt < 4; ++nt)
#pragma unroll
                for (int r = 0; r < 4; ++r)
                    s_x[(quad * 4 + r) * 768 + 512 + w * 64 + nt * 16 + l16] = (short)f2bf(acc[nt][r]);
        }
    }
    __syncthreads();

    // ---- coalesced 16B write-out: 768 contiguous frag8 chunks ----
    {
        unsigned short* xg = xout + (size_t)n0 * 768;
        for (int c = tid; c < TA * 96; c += 256)
            *(frag8*)(xg + c * 8) = *(const frag8*)(&s_x[c * 8]);
    }
}

// ---------------- Kernel B: transformer, 4 tokens/block = 12 rows (padded 16) ----------------
__global__ __launch_bounds__(256, 3)
void mha_ff_mfma(const unsigned short* __restrict__ xin,   // bf16 (NTOK x 768)
                 const unsigned short* __restrict__ pk,
                 const float* __restrict__ bqkv, const float* __restrict__ bout,
                 const float* __restrict__ ln1g, const float* __restrict__ ln1b,
                 const float* __restrict__ fb1,  const float* __restrict__ fb2,
                 const float* __restrict__ ln2g, const float* __restrict__ ln2b,
                 const int* __restrict__ positions,
                 float* __restrict__ out)
{
    constexpr int PA = 264;   // bf16 pitch, A-operand region (16 rows)
    constexpr int PQ = 776;   // bf16 pitch, qkv region (16 rows)
    constexpr int PF = 260;   // fp32 pitch (16 rows)
    const int tid = threadIdx.x;
    const int w = tid >> 6, lane = tid & 63;
    const int quad = lane >> 4, l16 = lane & 15;
    const int n0tok = blockIdx.x * TB;
    const unsigned short* xg = xin + (size_t)n0tok * 3 * D;

    __shared__ __align__(16) short s_a[16 * PA];    // 8448 B: x -> o -> y
    __shared__ __align__(16) char  Uq[25088];       // qkv -> s_f|s_h
    __shared__ float s_att[TB * NH * 9];            // 288

    short* qkv = (short*)Uq;
    float* s_f = (float*)Uq;
    short* s_h = (short*)(Uq + 16640);

    // ---- stage x bf16 (12 rows x 256) -> s_a, direct 16B copies ----
    for (int i = tid; i < 12 * 32; i += 256) {
        int row = i >> 5, col = (i & 31) * 8;
        *(frag8*)(&s_a[row * PA + col]) = *(const frag8*)(xg + row * 256 + col);
    }
    __syncthreads();

    float xres[16];    // x residual at this thread's GEMM2 epilogue positions

    // ---- GEMM1: qkv = x @ Wqkv + bias (M=16 padded, N=768; wave w: 192 cols) ----
    {
        f32x4 acc[12];
#pragma unroll
        for (int nt = 0; nt < 12; ++nt) {
            float bv = bqkv[w * 192 + nt * 16 + l16];
            acc[nt][0] = bv; acc[nt][1] = bv; acc[nt][2] = bv; acc[nt][3] = bv;
        }
        for (int kt = 0; kt < 8; ++kt) {
            frag8 a = *(const frag8*)(&s_a[l16 * PA + kt * 32 + quad * 8]);
#pragma unroll
            for (int nt = 0; nt < 12; ++nt) {
                frag8 b = *(const frag8*)(pk + PK_QKV + (((size_t)(w * 12 + nt) * 8 + kt) * 64 + lane) * 8);
                acc[nt] = __builtin_amdgcn_mfma_f32_16x16x32_bf16(a, b, acc[nt], 0, 0, 0);
            }
        }
        // snapshot x residual before o overwrites s_a
#pragma unroll
        for (int nt = 0; nt < 4; ++nt)
#pragma unroll
            for (int r = 0; r < 4; ++r)
                xres[nt * 4 + r] = bf2f(s_a[(quad * 4 + r) * PA + w * 64 + nt * 16 + l16]);
#pragma unroll
        for (int nt = 0; nt < 12; ++nt)
#pragma unroll
            for (int r = 0; r < 4; ++r) {
                int row = quad * 4 + r, col = w * 192 + nt * 16 + l16;
                qkv[row * PQ + col] = (short)f2bf(acc[nt][r]);
            }
    }
    __syncthreads();

    // ---- attention scores + softmax fused: one triple per thread ----
    for (int idx3 = tid; idx3 < TB * NH * 3; idx3 += 256) {   // 96 triples
        int tok = idx3 / 24, rem = idx3 % 24;
        int h = rem / 3, qr = rem % 3;
        const short* qp = qkv + (tok * 3 + qr) * PQ + h * HD;
        const short* k0 = qkv + (tok * 3 + 0) * PQ + D + h * HD;
        const short* k1 = qkv + (tok * 3 + 1) * PQ + D + h * HD;
        const short* k2 = qkv + (tok * 3 + 2) * PQ + D + h * HD;
        float s0 = 0.0f, s1 = 0.0f, s2 = 0.0f;
#pragma unroll
        for (int u = 0; u < HD; ++u) {
            float q = bf2f(qp[u]);
            s0 += q * bf2f(k0[u]);
            s1 += q * bf2f(k1[u]);
            s2 += q * bf2f(k2[u]);
        }
        const float sc = 1.0f / sqrtf((float)HD);
        s0 *= sc; s1 *= sc; s2 *= sc;
        float m = fmaxf(s0, fmaxf(s1, s2));
        float e0 = expf(s0 - m), e1 = expf(s1 - m), e2 = expf(s2 - m);
        float inv = 1.0f / (e0 + e1 + e2);
        s_att[idx3 * 3 + 0] = e0 * inv;
        s_att[idx3 * 3 + 1] = e1 * inv;
        s_att[idx3 * 3 + 2] = e2 * inv;
    }
    __syncthreads();

    // ---- o = att @ v -> s_a bf16 (over x; residual snapshotted in regs) ----
    {
        const int h = tid >> 5;
#pragma unroll
        for (int tok = 0; tok < TB; ++tok) {
            float v0 = bf2f(qkv[(tok * 3 + 0) * PQ + 2 * D + tid]);
            float v1 = bf2f(qkv[(tok * 3 + 1) * PQ + 2 * D + tid]);
            float v2 = bf2f(qkv[(tok * 3 + 2) * PQ + 2 * D + tid]);
#pragma unroll
            for (int qr = 0; qr < 3; ++qr) {
                const float* a = s_att + tok * 72 + h * 9 + qr * 3;
                s_a[(tok * 3 + qr) * PA + tid] = (short)f2bf(a[0] * v0 + a[1] * v1 + a[2] * v2);
            }
        }
    }
    __syncthreads();   // qkv dead (scores + v consumed); o live in s_a

    // ---- GEMM2: proj = o @ Wout + bias + x -> s_f fp32 (over dead qkv) ----
    {
        f32x4 acc[4];
#pragma unroll
        for (int nt = 0; nt < 4; ++nt) {
            float bv = bout[w * 64 + nt * 16 + l16];
            acc[nt][0] = bv; acc[nt][1] = bv; acc[nt][2] = bv; acc[nt][3] = bv;
        }
        for (int kt = 0; kt < 8; ++kt) {
            frag8 a = *(const frag8*)(&s_a[l16 * PA + kt * 32 + quad * 8]);
#pragma unroll
            for (int nt = 0; nt < 4; ++nt) {
                frag8 b = *(const frag8*)(pk + PK_OUT + (((size_t)(w * 4 + nt) * 8 + kt) * 64 + lane) * 8);
                acc[nt] = __builtin_amdgcn_mfma_f32_16x16x32_bf16(a, b, acc[nt], 0, 0, 0);
            }
        }
        __syncthreads();   // all A-reads of o done before s_f overwrites qkv region
#pragma unroll
        for (int nt = 0; nt < 4; ++nt)
#pragma unroll
            for (int r = 0; r < 4; ++r) {
                int row = quad * 4 + r, col = w * 64 + nt * 16 + l16;
                s_f[row * PF + col] = acc[nt][r] + xres[nt * 4 + r];
            }
    }
    __syncthreads();

    // ---- LN1 (wave w: rows w, w+4, w+8, w+12) -> y fp32 in s_f, y bf16 -> s_a ----
#pragma unroll
    for (int rr = 0; rr < 4; ++rr) {
        int row = w + rr * 4, col = lane * 4;
        float4 v = *(const float4*)(&s_f[row * PF + col]);
        float mean = wsum64(v.x + v.y + v.z + v.w) * (1.0f / 256.0f);
        float dx = v.x - mean, dy = v.y - mean, dz = v.z - mean, dw = v.w - mean;
        float var = wsum64(dx * dx + dy * dy + dz * dz + dw * dw) * (1.0f / 256.0f);
        float s = sqrtf(var + LN_EPS);
        float4 g = *(const float4*)(ln1g + col), b = *(const float4*)(ln1b + col);
        float y0 = dx / s * g.x + b.x, y1 = dy / s * g.y + b.y;
        float y2 = dz / s * g.z + b.z, y3 = dw / s * g.w + b.w;
        float4 yv; yv.x = y0; yv.y = y1; yv.z = y2; yv.w = y3;
        *(float4*)(&s_f[row * PF + col]) = yv;
        ushort4 bb; bb.x = f2bf(y0); bb.y = f2bf(y1); bb.z = f2bf(y2); bb.w = f2bf(y3);
        *(ushort4*)(&s_a[row * PA + col]) = bb;
    }
    __syncthreads();

    // ---- FF1: h = relu(y @ FW1 + b1) -> s_h bf16 ----
    {
        f32x4 acc[4];
#pragma unroll
        for (int nt = 0; nt < 4; ++nt) {
            float bv = fb1[w * 64 + nt * 16 + l16];
            acc[nt][0] = bv; acc[nt][1] = bv; acc[nt][2] = bv; acc[nt][3] = bv;
        }
        for (int kt = 0; kt < 8; ++kt) {
            frag8 a = *(const frag8*)(&s_a[l16 * PA + kt * 32 + quad * 8]);
#pragma unroll
            for (int nt = 0; nt < 4; ++nt) {
                frag8 b = *(const frag8*)(pk + PK_FF1 + (((size_t)(w * 4 + nt) * 8 + kt) * 64 + lane) * 8);
                acc[nt] = __builtin_amdgcn_mfma_f32_16x16x32_bf16(a, b, acc[nt], 0, 0, 0);
            }
        }
#pragma unroll
        for (int nt = 0; nt < 4; ++nt)
#pragma unroll
            for (int r = 0; r < 4; ++r) {
                int row = quad * 4 + r, col = w * 64 + nt * 16 + l16;
                s_h[row * PA + col] = (short)f2bf(fmaxf(acc[nt][r], 0.0f));
            }
    }
    __syncthreads();

    // ---- FF2 + residual -> s_f (in place) ----
    {
        f32x4 acc[4];
#pragma unroll
        for (int nt = 0; nt < 4; ++nt) {
            float bv = fb2[w * 64 + nt * 16 + l16];
            acc[nt][0] = bv; acc[nt][1] = bv; acc[nt][2] = bv; acc[nt][3] = bv;
        }
        for (int kt = 0; kt < 8; ++kt) {
            frag8 a = *(const frag8*)(&s_h[l16 * PA + kt * 32 + quad * 8]);
#pragma unroll
            for (int nt = 0; nt < 4; ++nt) {
                frag8 b = *(const frag8*)(pk + PK_FF2 + (((size_t)(w * 4 + nt) * 8 + kt) * 64 + lane) * 8);
                acc[nt] = __builtin_amdgcn_mfma_f32_16x16x32_bf16(a, b, acc[nt], 0, 0, 0);
            }
        }
#pragma unroll
        for (int nt = 0; nt < 4; ++nt)
#pragma unroll
            for (int r = 0; r < 4; ++r) {
                int row = quad * 4 + r, col = w * 64 + nt * 16 + l16;
                float y = s_f[row * PF + col];   // same lane reads then writes
                s_f[row * PF + col] = acc[nt][r] + y;
            }
    }
    __syncthreads();

    // ---- LN2 (in place) ----
#pragma unroll
    for (int rr = 0; rr < 4; ++rr) {
        int row = w + rr * 4, col = lane * 4;
        float4 v = *(const float4*)(&s_f[row * PF + col]);
        float mean = wsum64(v.x + v.y + v.z + v.w) * (1.0f / 256.0f);
        float dx = v.x - mean, dy = v.y - mean, dz = v.z - mean, dw = v.w - mean;
        float var = wsum64(dx * dx + dy * dy + dz * dz + dw * dw) * (1.0f / 256.0f);
        float s = sqrtf(var + LN_EPS);
        float4 g = *(const float4*)(ln2g + col), b = *(const float4*)(ln2b + col);
        float4 zv;
        zv.x = dx / s * g.x + b.x; zv.y = dy / s * g.y + b.y;
        zv.z = dz / s * g.z + b.z; zv.w = dw / s * g.w + b.w;
        *(float4*)(&s_f[row * PF + col]) = zv;
    }
    __syncthreads();

    // ---- modality mean + positional encodings ----
    {
        const int fi = tid >> 1;
        const float freq = expf(-logf(10000.0f) * (2.0f * fi) / (float)D);
#pragma unroll
        for (int t = 0; t < TB; ++t) {
            int n = n0tok + t;
            float m3 = (s_f[(3 * t) * PF + tid] + s_f[(3 * t + 1) * PF + tid] +
                        s_f[(3 * t + 2) * PF + tid]) / 3.0f;
            float p0 = (float)positions[2 * n], p1 = (float)positions[2 * n + 1];
            float a0 = p0 * freq, a1 = p1 * freq;
            float pe = (tid & 1) ? (cosf(a0) + cosf(a1)) : (sinf(a0) + sinf(a1));
            out[(size_t)n * D + tid] = m3 + pe;
        }
    }
}

extern "C" void kernel_launch(void* const* d_in, const int* in_sizes, int n_in,
                              void* d_out, int out_size, void* d_ws, size_t ws_size,
                              hipStream_t stream)
{
    const float* iq        = (const float*)d_in[0];
    const int*   positions = (const int*)d_in[1];
    const float* poi_coors = (const float*)d_in[2];
    const float* poi_embed = (const float*)d_in[3];
    const float* sp_w1     = (const float*)d_in[4];
    const float* sp_b1     = (const float*)d_in[5];
    const float* sp_w2     = (const float*)d_in[6];
    const float* sp_b2     = (const float*)d_in[7];
    const float* four_w    = (const float*)d_in[8];
    const float* four_b    = (const float*)d_in[9];
    const float* te_w      = (const float*)d_in[10];
    const float* te_b      = (const float*)d_in[11];
    const float* poi_ln_g  = (const float*)d_in[12];
    const float* poi_ln_b  = (const float*)d_in[13];
    const float* poi_w     = (const float*)d_in[14];
    const float* poi_b     = (const float*)d_in[15];
    const float* tok_emb   = (const float*)d_in[16];
    const float* tok_ln_g  = (const float*)d_in[17];
    const float* tok_ln_b  = (const float*)d_in[18];
    const float* tok_w     = (const float*)d_in[19];
    const float* tok_b     = (const float*)d_in[20];
    const float* mha_in_w  = (const float*)d_in[21];
    const float* mha_in_b  = (const float*)d_in[22];
    const float* mha_out_w = (const float*)d_in[23];
    const float* mha_out_b = (const float*)d_in[24];
    const float* ln1_g     = (const float*)d_in[25];
    const float* ln1_b     = (const float*)d_in[26];
    const float* ff_w1     = (const float*)d_in[27];
    const float* ff_b1     = (const float*)d_in[28];
    const float* ff_w2     = (const float*)d_in[29];
    const float* ff_b2     = (const float*)d_in[30];
    const float* ln2_g     = (const float*)d_in[31];
    const float* ln2_b     = (const float*)d_in[32];

    unsigned short* pkw = (unsigned short*)d_ws;                     // 1.38 MB packed weights
    unsigned short* xws = (unsigned short*)((char*)d_ws + PK_TOTAL * 2);  // x bf16, 6.3 MB

    pack_weights<<<NTILES / 4, 256, 0, stream>>>(
        mha_in_w, mha_out_w, ff_w1, ff_w2, sp_w2, te_w, poi_w, tok_w, pkw);

    embed_mfma<<<NTOK / TA, 256, 0, stream>>>(
        iq, poi_coors, poi_embed, sp_w1, sp_b1, sp_b2, four_w, four_b, te_b,
        poi_ln_g, poi_ln_b, poi_b, tok_emb, tok_ln_g, tok_ln_b, tok_b,
        pkw, xws);

    mha_ff_mfma<<<NTOK / TB, 256, 0, stream>>>(
        xws, pkw, mha_in_b, mha_out_b, ln1_g, ln1_b,
        ff_b1, ff_b2, ln2_g, ln2_b, positions, (float*)d_out);
}